// Round 11
// baseline (417.932 us; speedup 1.0000x reference)
//
#include <hip/hip_runtime.h>

#define NB    512
#define CIN   12
#define TIN   5000
#define C1    32
#define T1    496
#define T2    95
#define LATD  32
#define HIDD  64

// workspace layout (float offsets)
#define OFS_STATS 0        // 256 floats
#define OFS_W1P   256      // 12*50*32 = 19200, layout [ic][p][j][oc] (polyphase)
#define OFS_W2P   19456    // 32*25*32 = 25600, layout [ic][p][j][oc] (polyphase)
#define OFS_Y1    45056    // 512*32*496 = 8126464
#define OFS_Y2    8171520  // 512*32*95  = 1556480
#define OFS_XS    OFS_Y1   // xs[95][512][32] aliases y1 (y1 dead after conv2)

// ---------------- prep: zero stats + repack weights (polyphase) ----------------
__global__ void prep_kernel(const float* __restrict__ w1, const float* __restrict__ w2,
                            float* __restrict__ ws) {
    int idx = blockIdx.x * 256 + threadIdx.x;
    if (idx < 256) ws[idx] = 0.f;
    int j = idx - 256;
    if (j >= 0 && j < 19200) {            // [ic][p][j][oc], oc fastest
        int ic = j / 1600, r = j % 1600;
        int p = r / 160, rr = r % 160, jj = rr / 32, oc = rr % 32;
        ws[OFS_W1P + j] = w1[oc * 600 + ic * 50 + 10 * jj + p];
    }
    int j2 = idx - 19456;
    if (j2 >= 0 && j2 < 25600) {
        int ic = j2 / 800, r = j2 % 800;
        int p = r / 160, rr = r % 160, jj = rr / 32, oc = rr % 32;
        ws[OFS_W2P + j2] = w2[oc * 800 + ic * 25 + 5 * jj + p];
    }
}

// ---------------- conv1 + bias, fused BN1 stats (polyphase, wide-t) ------------
// R11: per-CU accounting showed the LDS pipe (3.93M ds_read_b128 ~ 77us) binds,
// not VALU issue (62us floor) — explains occupancy-insensitivity (R1/R2/R4).
// Per-thread tile 4 oc x 16 t: per phase 5 x-b128 + 5 w-b128 per 320 FMA
// (2x fewer LDS reads/FMA -> LDS-pipe ~48us < VALU ~71us).
// block 128 = 8 ocg x 16 tg, grid 1024 (b x 2 t-tiles of 256; same output tiling
// as R9 -> no R4-style write amplification). x LDS [10][324] with +4-per-16 skew:
// lane base 20*tg -> bank quads {0,20,8,28,16,4,24,12}, conflict-free; the 5th
// read at 20*(tg+1) is the next group's first quad, also all-distinct.
__global__ __launch_bounds__(128, 2) void conv1_kernel(const float* __restrict__ x,
                                                       const float* __restrict__ b1,
                                                       float* __restrict__ ws) {
    const float* w1p = ws + OFS_W1P;
    float* y1 = ws + OFS_Y1;
    float* stats = ws + OFS_STATS;
    int b  = blockIdx.x >> 1;
    int t0 = (blockIdx.x & 1) * 256;
    int tid = threadIdx.x;
    int ocg = tid & 7, tg = tid >> 3;         // 8 ocg x 16 tg (16 t each)
    int oc0 = ocg * 4, lt0 = tg * 16;

    __shared__ __align__(16) float xs_s[2][3240];   // [10][324] skewed polyphase
    __shared__ __align__(16) float ws_s[2][1600];   // [p][j][oc] 10*5*32
    __shared__ float sred[128];

    float acc[4][16];
#pragma unroll
    for (int a = 0; a < 4; ++a)
#pragma unroll
        for (int c = 0; c < 16; ++c) acc[a][c] = 0.f;

    const float* xb = x + (size_t)b * (CIN * TIN) + t0 * 10;
    int nvalid = TIN - t0 * 10;               // 5000 or 2440; window = 2600

    float4 px[6];
    float4 pw[4];

    auto fetch = [&](int ic) {
#pragma unroll
        for (int j = 0; j < 6; ++j) {
            int i = tid + j * 128;
            if (i < 650) {
                int src = 4 * i;
                const float* gp = xb + ic * TIN + src;
                float4 v;
                if (src + 4 <= nvalid) {
                    v = *(const float4*)gp;
                } else {
                    v.x = (src + 0 < nvalid) ? gp[0] : 0.f;
                    v.y = (src + 1 < nvalid) ? gp[1] : 0.f;
                    v.z = (src + 2 < nvalid) ? gp[2] : 0.f;
                    v.w = (src + 3 < nvalid) ? gp[3] : 0.f;
                }
                px[j] = v;
            }
        }
#pragma unroll
        for (int j = 0; j < 4; ++j) {
            int i = tid + j * 128;
            if (i < 400) pw[j] = *(const float4*)(w1p + ic * 1600 + 4 * i);
        }
    };

    auto stage = [&](int cur) {
#pragma unroll
        for (int j = 0; j < 6; ++j) {
            int i = tid + j * 128;
            if (i < 650) {
                int g = 4 * i;                // window position of px[j].x
                int col = g / 10, p = g - 10 * col;
                float vals[4] = {px[j].x, px[j].y, px[j].z, px[j].w};
#pragma unroll
                for (int m = 0; m < 4; ++m) {
                    int pm = p + m;
                    int rr = (pm >= 10) ? pm - 10 : pm;
                    int cc = col + ((pm >= 10) ? 1 : 0);        // 0..259
                    int sc = cc + 4 * (cc >> 4);                // skew +4 per 16
                    xs_s[cur][rr * 324 + sc] = vals[m];
                }
            }
        }
#pragma unroll
        for (int j = 0; j < 4; ++j) {
            int i = tid + j * 128;
            if (i < 400) *(float4*)&ws_s[cur][4 * i] = pw[j];
        }
    };

    fetch(0);
    stage(0);                                 // buf0 <- ic 0
    fetch(1);
    __syncthreads();                          // buf0 visible to all

    for (int ic = 0; ic < CIN; ++ic) {
        int cur = ic & 1;
        if (ic + 1 < CIN) stage(cur ^ 1);     // stage next while computing cur
        if (ic + 2 < CIN) fetch(ic + 2);      // global loads fly during compute

#pragma unroll 2
        for (int p = 0; p < 10; ++p) {
            const float* xr = &xs_s[cur][p * 324 + 20 * tg];
            float4 x0 = *(const float4*)(xr);
            float4 x1 = *(const float4*)(xr + 4);
            float4 x2 = *(const float4*)(xr + 8);
            float4 x3 = *(const float4*)(xr + 12);
            float4 x4 = *(const float4*)&xs_s[cur][p * 324 + 20 * (tg + 1)];
            float xv[20] = {x0.x, x0.y, x0.z, x0.w,
                            x1.x, x1.y, x1.z, x1.w,
                            x2.x, x2.y, x2.z, x2.w,
                            x3.x, x3.y, x3.z, x3.w,
                            x4.x, x4.y, x4.z, x4.w};
            const float* wr = &ws_s[cur][p * 160 + oc0];
            float4 w0 = *(const float4*)(wr);
            float4 w1v = *(const float4*)(wr + 32);
            float4 w2v = *(const float4*)(wr + 64);
            float4 w3v = *(const float4*)(wr + 96);
            float4 w4v = *(const float4*)(wr + 128);
            float wj[5][4] = {{w0.x, w0.y, w0.z, w0.w},
                              {w1v.x, w1v.y, w1v.z, w1v.w},
                              {w2v.x, w2v.y, w2v.z, w2v.w},
                              {w3v.x, w3v.y, w3v.z, w3v.w},
                              {w4v.x, w4v.y, w4v.z, w4v.w}};
#pragma unroll
            for (int j = 0; j < 5; ++j)
#pragma unroll
                for (int jt = 0; jt < 16; ++jt) {
                    float xx = xv[jt + j];
#pragma unroll
                    for (int jo = 0; jo < 4; ++jo)
                        acc[jo][jt] = fmaf(wj[j][jo], xx, acc[jo][jt]);
                }
        }
        __syncthreads();                      // stage(ic+1) visible; buf[cur] free
    }

    float bias[4];
#pragma unroll
    for (int jo = 0; jo < 4; ++jo) bias[jo] = b1[oc0 + jo];

    bool tvalid = (t0 + lt0) <= (T1 - 16);    // tile-1 tg15 (t 496..511) invalid
    float psum[4], psq[4];
#pragma unroll
    for (int jo = 0; jo < 4; ++jo) {
        float s = 0.f, q = 0.f;
        if (tvalid) {
            float tmp[16];
#pragma unroll
            for (int jt = 0; jt < 16; ++jt) {
                float v = acc[jo][jt] + bias[jo];
                tmp[jt] = v; s += v; q = fmaf(v, v, q);
            }
            float* yrow = y1 + (size_t)(b * 32 + oc0 + jo) * T1 + t0 + lt0;
#pragma unroll
            for (int k = 0; k < 4; ++k) {
                float4 o; o.x = tmp[4 * k]; o.y = tmp[4 * k + 1];
                o.z = tmp[4 * k + 2]; o.w = tmp[4 * k + 3];
                *(float4*)(yrow + 4 * k) = o;
            }
        }
        psum[jo] = s; psq[jo] = q;
    }
    // reduce over tg within wave (lanes with same ocg are lane = ocg + 8*m)
#pragma unroll
    for (int off = 32; off >= 8; off >>= 1) {
#pragma unroll
        for (int jo = 0; jo < 4; ++jo) {
            psum[jo] += __shfl_down(psum[jo], off, 64);
            psq[jo]  += __shfl_down(psq[jo],  off, 64);
        }
    }
    int lane = tid & 63, wvi = tid >> 6;      // 2 waves
    if (lane < 8) {
#pragma unroll
        for (int jo = 0; jo < 4; ++jo) {
            sred[((wvi * 8 + lane) * 4 + jo) * 2 + 0] = psum[jo];
            sred[((wvi * 8 + lane) * 4 + jo) * 2 + 1] = psq[jo];
        }
    }
    __syncthreads();
    if (tid < 64) {
        int oc = tid >> 1, which = tid & 1;
        int og = oc >> 2, jo = oc & 3;        // oc = 4*ocg + jo
        float v = 0.f;
#pragma unroll
        for (int w = 0; w < 2; ++w)
            v += sred[((w * 8 + og) * 4 + jo) * 2 + which];
        atomicAdd(&stats[which * 32 + oc], v);
    }
}

// ---------------- conv2 (BN1+ReLU folded at stage time) + BN2 stats ------------
// R9 form, frozen: in-block ic-split, 384 threads = two 192-thread halves, each
// running the bit-identical R7 dbuf loop over 16 ics; half 1 parks partials in
// LDS; half 0 combines + bias + y2 write + BN2 stats.
__global__ __launch_bounds__(384, 2) void conv2_kernel(const float* __restrict__ b2,
                                                       const float* __restrict__ g1,
                                                       const float* __restrict__ be1,
                                                       float* __restrict__ ws) {
    const float* w2p = ws + OFS_W2P;
    const float* y1 = ws + OFS_Y1;
    float* y2 = ws + OFS_Y2;
    float* stats = ws + OFS_STATS;
    int b = blockIdx.x;
    int tid = threadIdx.x;
    int hf = (tid >= 192) ? 1 : 0;
    int ltid = tid - hf * 192;
    int icbase = hf * 16;
    int ocg = ltid & 7, tg = ltid >> 3;
    int oc0 = ocg * 4, lt0 = tg * 4;

    __shared__ __align__(16) float a1s[2][2][500];   // [hf][buf][5*100] polyphase
    __shared__ __align__(16) float w2s[2][2][800];   // [hf][buf][p*j*oc]
    __shared__ __align__(16) float comb[16 * 192];   // half-1 partials
    __shared__ float sred[192];
    __shared__ float bns[64];                        // BN1 scale/shift

    if (tid < 32) {
        float mean = stats[tid] * (1.f / 253952.f);
        float var  = stats[32 + tid] * (1.f / 253952.f) - mean * mean;
        float s = g1[tid] * rsqrtf(var + 1e-5f);
        bns[tid]      = s;
        bns[32 + tid] = be1[tid] - mean * s;
    }

    float acc[4][4];
#pragma unroll
    for (int a = 0; a < 4; ++a)
#pragma unroll
        for (int c = 0; c < 4; ++c) acc[a][c] = 0.f;

    float4 py, pw0, pw1;
    auto fetch = [&](int k) {
        int ic = icbase + k;
        const float* yrow = y1 + (size_t)(b * 32 + ic) * T1;
        if (ltid < 124) py = *(const float4*)(yrow + 4 * ltid);
        pw0 = *(const float4*)(w2p + ic * 800 + 4 * ltid);          // ltid < 192 < 200
        if (ltid < 8) pw1 = *(const float4*)(w2p + ic * 800 + 4 * (ltid + 192));
    };

    auto stage = [&](int k, int cur) {
        int ic = icbase + k;
        if (ltid < 124) {
            float s1 = bns[ic], sh1 = bns[32 + ic];
            float vals[4];
            vals[0] = fmaxf(fmaf(py.x, s1, sh1), 0.f);
            vals[1] = fmaxf(fmaf(py.y, s1, sh1), 0.f);
            vals[2] = fmaxf(fmaf(py.z, s1, sh1), 0.f);
            vals[3] = fmaxf(fmaf(py.w, s1, sh1), 0.f);
            int g = 4 * ltid;
            int col = g / 5, p = g - 5 * col;
#pragma unroll
            for (int m = 0; m < 4; ++m) {
                int pm = p + m;
                int rr = (pm >= 5) ? pm - 5 : pm;
                int cc = col + ((pm >= 5) ? 1 : 0);
                a1s[hf][cur][rr * 100 + cc] = vals[m];
            }
        }
        *(float4*)&w2s[hf][cur][4 * ltid] = pw0;
        if (ltid < 8) *(float4*)&w2s[hf][cur][4 * (ltid + 192)] = pw1;
    };

    fetch(0);
    __syncthreads();                          // bns visible
    stage(0, 0);
    fetch(1);
    __syncthreads();                          // buf0 visible

    for (int k = 0; k < 16; ++k) {
        int cur = k & 1;
        if (k + 1 < 16) stage(k + 1, cur ^ 1);    // stage next while computing cur
        if (k + 2 < 16) fetch(k + 2);             // loads fly during compute

#pragma unroll 2
        for (int p = 0; p < 5; ++p) {
            const float* xr = &a1s[hf][cur][p * 100 + 4 * tg];
            float4 xa = *(const float4*)(xr);
            float4 xbv = *(const float4*)(xr + 4);
            float xv[8] = {xa.x, xa.y, xa.z, xa.w, xbv.x, xbv.y, xbv.z, xbv.w};
            const float* wr = &w2s[hf][cur][p * 160 + oc0];
            float4 w0 = *(const float4*)(wr);
            float4 w1v = *(const float4*)(wr + 32);
            float4 w2v = *(const float4*)(wr + 64);
            float4 w3v = *(const float4*)(wr + 96);
            float4 w4v = *(const float4*)(wr + 128);
            float wj[5][4] = {{w0.x, w0.y, w0.z, w0.w},
                              {w1v.x, w1v.y, w1v.z, w1v.w},
                              {w2v.x, w2v.y, w2v.z, w2v.w},
                              {w3v.x, w3v.y, w3v.z, w3v.w},
                              {w4v.x, w4v.y, w4v.z, w4v.w}};
#pragma unroll
            for (int j = 0; j < 5; ++j)
#pragma unroll
                for (int jt = 0; jt < 4; ++jt) {
                    float xx = xv[jt + j];
#pragma unroll
                    for (int jo = 0; jo < 4; ++jo)
                        acc[jo][jt] = fmaf(wj[j][jo], xx, acc[jo][jt]);
                }
        }
        __syncthreads();                      // stage(k+1) visible; buf[cur] free
    }

    // half 1 parks partials (stride-1 across lanes: conflict-free)
    if (hf == 1) {
#pragma unroll
        for (int jo = 0; jo < 4; ++jo)
#pragma unroll
            for (int jt = 0; jt < 4; ++jt)
                comb[(jo * 4 + jt) * 192 + ltid] = acc[jo][jt];
    }
    __syncthreads();

    if (hf == 0) {
        float bias[4];
#pragma unroll
        for (int jo = 0; jo < 4; ++jo) bias[jo] = b2[oc0 + jo];

        float psum[4], psq[4];
#pragma unroll
        for (int jo = 0; jo < 4; ++jo) {
            float s = 0.f, q = 0.f;
#pragma unroll
            for (int jt = 0; jt < 4; ++jt) {
                int t2 = lt0 + jt;
                if (t2 < T2) {
                    float v = acc[jo][jt] + comb[(jo * 4 + jt) * 192 + ltid] + bias[jo];
                    y2[(size_t)(b * 32 + oc0 + jo) * T2 + t2] = v;
                    s += v; q = fmaf(v, v, q);
                }
            }
            psum[jo] = s; psq[jo] = q;
        }
#pragma unroll
        for (int off = 32; off >= 8; off >>= 1) {
#pragma unroll
            for (int jo = 0; jo < 4; ++jo) {
                psum[jo] += __shfl_down(psum[jo], off, 64);
                psq[jo]  += __shfl_down(psq[jo],  off, 64);
            }
        }
        int lane = ltid & 63, wvi = ltid >> 6;   // 3 waves
        if (lane < 8) {
#pragma unroll
            for (int jo = 0; jo < 4; ++jo) {
                sred[((wvi * 8 + lane) * 4 + jo) * 2 + 0] = psum[jo];
                sred[((wvi * 8 + lane) * 4 + jo) * 2 + 1] = psq[jo];
            }
        }
    }
    __syncthreads();
    if (tid < 64) {
        int oc = tid >> 1, which = tid & 1;
        int og = oc >> 2, jo = oc & 3;
        float v = 0.f;
#pragma unroll
        for (int w = 0; w < 3; ++w)
            v += sred[((w * 8 + og) * 4 + jo) * 2 + which];
        atomicAdd(&stats[64 + which * 32 + oc], v);
    }
}

// ---------------- projection + LayerNorm, writes xs[t][b][l] ----------------
// R9 form (standalone; R10's fusion into scan was neutral -> keep best measured).
__global__ __launch_bounds__(256, 2) void proj_kernel(const float* __restrict__ g2,
                                                      const float* __restrict__ be2,
                                                      const float* __restrict__ pw,
                                                      const float* __restrict__ pb,
                                                      const float* __restrict__ lng,
                                                      const float* __restrict__ lnb,
                                                      float* __restrict__ ws) {
    int b = blockIdx.x;
    int tid = threadIdx.x;
    __shared__ float a2s[3040];       // [f][t]
    __shared__ float pws[1056];       // [l][33]
    __shared__ float bns2[64];
    const float* stats = ws + OFS_STATS;
    const float* y2 = ws + OFS_Y2 + (size_t)b * (32 * T2);
    float* xsg = ws + OFS_XS;

    if (tid < 32) {
        float mean = stats[64 + tid] * (1.f / 48640.f);
        float var  = stats[96 + tid] * (1.f / 48640.f) - mean * mean;
        float s = g2[tid] * rsqrtf(var + 1e-5f);
        bns2[tid]      = s;
        bns2[32 + tid] = be2[tid] - mean * s;
    }
    __syncthreads();

    for (int i = tid; i < 3040; i += 256) {
        int f = i / 95;
        a2s[i] = fmaxf(fmaf(y2[i], bns2[f], bns2[32 + f]), 0.f);
    }
    for (int i = tid; i < 1024; i += 256)
        pws[(i >> 5) * 33 + (i & 31)] = pw[i];

    int l = tid & 31, ts = tid >> 5;
    float pbv = pb[l], lg = lng[l], lb = lnb[l];
    __syncthreads();

    for (int it = 0; it < 12; ++it) {
        int t = ts + 8 * it;
        if (t < T2) {
            float v = pbv;
#pragma unroll
            for (int f = 0; f < 32; ++f)
                v = fmaf(a2s[f * T2 + t], pws[l * 33 + f], v);
            float sum = v;
#pragma unroll
            for (int off = 16; off >= 1; off >>= 1) sum += __shfl_xor(sum, off, 64);
            float mean = sum * (1.f / 32.f);
            float d = v - mean;
            float q = d * d;
#pragma unroll
            for (int off = 16; off >= 1; off >>= 1) q += __shfl_xor(q, off, 64);
            float o = d * rsqrtf(q * (1.f / 32.f) + 1e-5f) * lg + lb;
            xsg[(size_t)t * (NB * 32) + b * 32 + l] = o;
        }
    }
}

// ---------------- PLRNN scan + pooled mean + output projection ----------------
// R9 form (global xs reads with 1-step register prefetch).
__global__ __launch_bounds__(64)
__attribute__((amdgpu_waves_per_eu(1, 1)))
void scan_kernel(const float* __restrict__ Am,
                 const float* __restrict__ Wm,
                 const float* __restrict__ hbp,
                 const float* __restrict__ ow,
                 const float* __restrict__ ob,
                 const float* __restrict__ ws,
                 float* __restrict__ out) {
    int b = blockIdx.x;
    int lane = threadIdx.x;
    int l = lane & 31, half = lane >> 5;
    __shared__ __align__(16) float hs[32];
    __shared__ __align__(16) float hds[64];
    __shared__ float ows[1056];

    float Wc[32], WT[32], Ah[16];
#pragma unroll
    for (int j = 0; j < 32; ++j) Wc[j] = Wm[j * HIDD + lane];          // W[j][lane]
#pragma unroll
    for (int m = 0; m < 32; ++m) WT[m] = Wm[l * HIDD + half * 32 + m]; // W[l][m-half]
#pragma unroll
    for (int j = 0; j < 16; ++j) Ah[j] = Am[l * 32 + half * 16 + j];   // A[l][j-half]
    float hbv = hbp[lane];
    for (int i = lane; i < 1024; i += 64)
        ows[(i >> 5) * 33 + (i & 31)] = ow[i];

    const float* xsg = ws + OFS_XS + b * 32;
    if (lane < 32) hs[l] = 0.f;
    float xv = xsg[l];
    float pool = 0.f;
    __syncthreads();

    for (int t = 0; t < T2; ++t) {
        __syncthreads();
        float4 hv[8];
#pragma unroll
        for (int q = 0; q < 8; ++q) hv[q] = *(const float4*)&hs[4 * q];
        float a0 = hbv, a1 = 0.f, a2 = 0.f, a3 = 0.f;
#pragma unroll
        for (int q = 0; q < 8; ++q) {
            a0 = fmaf(Wc[4 * q + 0], hv[q].x, a0);
            a1 = fmaf(Wc[4 * q + 1], hv[q].y, a1);
            a2 = fmaf(Wc[4 * q + 2], hv[q].z, a2);
            a3 = fmaf(Wc[4 * q + 3], hv[q].w, a3);
        }
        float hid = fmaxf((a0 + a1) + (a2 + a3), 0.f);
        float4 hl[4];
#pragma unroll
        for (int q = 0; q < 4; ++q) hl[q] = *(const float4*)&hs[half * 16 + 4 * q];
        float l0 = 0.f, l1 = 0.f;
#pragma unroll
        for (int q = 0; q < 4; ++q) {
            l0 = fmaf(Ah[4 * q + 0], hl[q].x, l0);
            l1 = fmaf(Ah[4 * q + 1], hl[q].y, l1);
            l0 = fmaf(Ah[4 * q + 2], hl[q].z, l0);
            l1 = fmaf(Ah[4 * q + 3], hl[q].w, l1);
        }
        float lin = l0 + l1;
        hds[lane] = hid;
        __syncthreads();
        float n0 = 0.f, n1 = 0.f, n2 = 0.f, n3 = 0.f;
#pragma unroll
        for (int q = 0; q < 8; ++q) {
            float4 d4 = *(const float4*)&hds[half * 32 + 4 * q];
            n0 = fmaf(WT[4 * q + 0], d4.x, n0);
            n1 = fmaf(WT[4 * q + 1], d4.y, n1);
            n2 = fmaf(WT[4 * q + 2], d4.z, n2);
            n3 = fmaf(WT[4 * q + 3], d4.w, n3);
        }
        float part = (n0 + n1) + (n2 + n3) + lin;
        part += __shfl_xor(part, 32, 64);
        float hnew = part + xv;
        pool += hnew;
        if (t + 1 < T2) xv = xsg[(size_t)(t + 1) * (NB * 32) + l];
        if (lane < 32) hs[l] = hnew;
    }

    __syncthreads();
    if (lane < 32) hs[l] = pool * (1.f / 95.f);
    __syncthreads();
    if (lane < 32) {
        float4 p0 = *(const float4*)&hs[0];
        float4 p1 = *(const float4*)&hs[4];
        float4 p2 = *(const float4*)&hs[8];
        float4 p3 = *(const float4*)&hs[12];
        float4 p4 = *(const float4*)&hs[16];
        float4 p5 = *(const float4*)&hs[20];
        float4 p6 = *(const float4*)&hs[24];
        float4 p7 = *(const float4*)&hs[28];
        float o = ob[l];
        const float* owr = &ows[l * 33];
        o = fmaf(owr[0],  p0.x, o); o = fmaf(owr[1],  p0.y, o);
        o = fmaf(owr[2],  p0.z, o); o = fmaf(owr[3],  p0.w, o);
        o = fmaf(owr[4],  p1.x, o); o = fmaf(owr[5],  p1.y, o);
        o = fmaf(owr[6],  p1.z, o); o = fmaf(owr[7],  p1.w, o);
        o = fmaf(owr[8],  p2.x, o); o = fmaf(owr[9],  p2.y, o);
        o = fmaf(owr[10], p2.z, o); o = fmaf(owr[11], p2.w, o);
        o = fmaf(owr[12], p3.x, o); o = fmaf(owr[13], p3.y, o);
        o = fmaf(owr[14], p3.z, o); o = fmaf(owr[15], p3.w, o);
        o = fmaf(owr[16], p4.x, o); o = fmaf(owr[17], p4.y, o);
        o = fmaf(owr[18], p4.z, o); o = fmaf(owr[19], p4.w, o);
        o = fmaf(owr[20], p5.x, o); o = fmaf(owr[21], p5.y, o);
        o = fmaf(owr[22], p5.z, o); o = fmaf(owr[23], p5.w, o);
        o = fmaf(owr[24], p6.x, o); o = fmaf(owr[25], p6.y, o);
        o = fmaf(owr[26], p6.z, o); o = fmaf(owr[27], p6.w, o);
        o = fmaf(owr[28], p7.x, o); o = fmaf(owr[29], p7.y, o);
        o = fmaf(owr[30], p7.z, o); o = fmaf(owr[31], p7.w, o);
        out[b * 32 + l] = o;
    }
}

extern "C" void kernel_launch(void* const* d_in, const int* in_sizes, int n_in,
                              void* d_out, int out_size, void* d_ws, size_t ws_size,
                              hipStream_t stream) {
    (void)in_sizes; (void)n_in; (void)out_size; (void)ws_size;
    const float* x   = (const float*)d_in[0];
    const float* w1  = (const float*)d_in[1];
    const float* b1  = (const float*)d_in[2];
    const float* g1  = (const float*)d_in[3];
    const float* be1 = (const float*)d_in[4];
    const float* w2  = (const float*)d_in[5];
    const float* b2  = (const float*)d_in[6];
    const float* g2  = (const float*)d_in[7];
    const float* be2 = (const float*)d_in[8];
    const float* pw  = (const float*)d_in[9];
    const float* pb  = (const float*)d_in[10];
    const float* lng = (const float*)d_in[11];
    const float* lnb = (const float*)d_in[12];
    const float* Am  = (const float*)d_in[13];
    const float* Wm  = (const float*)d_in[14];
    const float* hb  = (const float*)d_in[15];
    const float* ow  = (const float*)d_in[16];
    const float* ob  = (const float*)d_in[17];
    float* ws  = (float*)d_ws;
    float* out = (float*)d_out;

    prep_kernel<<<176, 256, 0, stream>>>(w1, w2, ws);
    conv1_kernel<<<1024, 128, 0, stream>>>(x, b1, ws);
    conv2_kernel<<<512, 384, 0, stream>>>(b2, g1, be1, ws);
    proj_kernel<<<512, 256, 0, stream>>>(g2, be2, pw, pb, lng, lnb, ws);
    scan_kernel<<<512, 64, 0, stream>>>(Am, Wm, hb, ow, ob, ws, out);
}

// Round 12
// 401.554 us; speedup vs baseline: 1.0408x; 1.0408x over previous
//
#include <hip/hip_runtime.h>

#define NB    512
#define CIN   12
#define TIN   5000
#define C1    32
#define T1    496
#define T2    95
#define LATD  32
#define HIDD  64

// workspace layout (float offsets)
#define OFS_STATS 0        // 256 floats
#define OFS_W1P   256      // 12*50*32 = 19200, layout [ic][p][j][oc] (polyphase)
#define OFS_W2P   19456    // 32*25*32 = 25600, layout [ic][p][j][oc] (polyphase)
#define OFS_Y1    45056    // 512*32*496 = 8126464
#define OFS_Y2    8171520  // 512*32*95  = 1556480
#define OFS_XS    OFS_Y1   // xs[95][512][32] aliases y1 (y1 dead after conv2)

// ---------------- prep: zero stats + repack weights (polyphase) ----------------
__global__ void prep_kernel(const float* __restrict__ w1, const float* __restrict__ w2,
                            float* __restrict__ ws) {
    int idx = blockIdx.x * 256 + threadIdx.x;
    if (idx < 256) ws[idx] = 0.f;
    int j = idx - 256;
    if (j >= 0 && j < 19200) {            // [ic][p][j][oc], oc fastest
        int ic = j / 1600, r = j % 1600;
        int p = r / 160, rr = r % 160, jj = rr / 32, oc = rr % 32;
        ws[OFS_W1P + j] = w1[oc * 600 + ic * 50 + 10 * jj + p];
    }
    int j2 = idx - 19456;
    if (j2 >= 0 && j2 < 25600) {
        int ic = j2 / 800, r = j2 % 800;
        int p = r / 160, rr = r % 160, jj = rr / 32, oc = rr % 32;
        ws[OFS_W2P + j2] = w2[oc * 800 + ic * 25 + 5 * jj + p];
    }
}

// ---------------- conv1 + bias, fused BN1 stats (polyphase, 1-barrier dbuf) ----
// R9 form, FROZEN: ~150.4 us, VGPR 64, VALUBusy ~59%, occupancy ~33%, conflicts
// 1.0M. R11 proved the occupancy map: flat above 2 waves/SIMD, cliff below;
// the wide-t LDS-read reduction costs VGPR 128 -> 1.5 waves/SIMD -> regression.
__global__ __launch_bounds__(256, 4) void conv1_kernel(const float* __restrict__ x,
                                                       const float* __restrict__ b1,
                                                       float* __restrict__ ws) {
    const float* w1p = ws + OFS_W1P;
    float* y1 = ws + OFS_Y1;
    float* stats = ws + OFS_STATS;
    int b  = blockIdx.x >> 1;
    int t0 = (blockIdx.x & 1) * 256;
    int tid = threadIdx.x;
    int ocg = tid & 7, tg = tid >> 3;         // 8 ocg x 32 tg
    int oc0 = ocg * 4, lt0 = tg * 8;

    __shared__ __align__(16) float xs_s[2][2680];   // [10][268] polyphase, dbuf
    __shared__ __align__(16) float ws_s[2][1600];   // [p][j][oc] 10*5*32
    __shared__ float sred[256];

    float acc[4][8];
#pragma unroll
    for (int a = 0; a < 4; ++a)
#pragma unroll
        for (int c = 0; c < 8; ++c) acc[a][c] = 0.f;

    const float* xb = x + (size_t)b * (CIN * TIN) + t0 * 10;
    int nvalid = TIN - t0 * 10;               // 5000 or 2440

    float4 px[3];
    float4 pw[2];

    auto fetch = [&](int ic) {
#pragma unroll
        for (int j = 0; j < 3; ++j) {
            int i = tid + j * 256;
            if (i < 650) {
                int src = 4 * i;
                const float* gp = xb + ic * TIN + src;
                float4 v;
                if (src + 4 <= nvalid) {
                    v = *(const float4*)gp;
                } else {
                    v.x = (src + 0 < nvalid) ? gp[0] : 0.f;
                    v.y = (src + 1 < nvalid) ? gp[1] : 0.f;
                    v.z = (src + 2 < nvalid) ? gp[2] : 0.f;
                    v.w = (src + 3 < nvalid) ? gp[3] : 0.f;
                }
                px[j] = v;
            }
        }
#pragma unroll
        for (int j = 0; j < 2; ++j) {
            int i = tid + j * 256;
            if (i < 400) pw[j] = *(const float4*)(w1p + ic * 1600 + 4 * i);
        }
    };

    auto stage = [&](int cur) {
#pragma unroll
        for (int j = 0; j < 3; ++j) {
            int i = tid + j * 256;
            if (i < 650) {
                int g = 4 * i;                // window position of px[j].x
                int col = g / 10, p = g - 10 * col;
                float vals[4] = {px[j].x, px[j].y, px[j].z, px[j].w};
#pragma unroll
                for (int m = 0; m < 4; ++m) {
                    int pm = p + m;
                    int rr = (pm >= 10) ? pm - 10 : pm;
                    int cc = col + ((pm >= 10) ? 1 : 0);
                    xs_s[cur][rr * 268 + cc] = vals[m];
                }
            }
        }
#pragma unroll
        for (int j = 0; j < 2; ++j) {
            int i = tid + j * 256;
            if (i < 400) *(float4*)&ws_s[cur][4 * i] = pw[j];
        }
    };

    fetch(0);
    stage(0);                                 // buf0 <- ic 0
    fetch(1);
    __syncthreads();                          // buf0 visible to all

    for (int ic = 0; ic < CIN; ++ic) {
        int cur = ic & 1;
        if (ic + 1 < CIN) stage(cur ^ 1);     // stage next while computing cur
        if (ic + 2 < CIN) fetch(ic + 2);      // global loads fly during compute

#pragma unroll 2
        for (int p = 0; p < 10; ++p) {
            const float* xr = &xs_s[cur][p * 268 + 8 * tg];
            float4 xa = *(const float4*)(xr);
            float4 xbv = *(const float4*)(xr + 4);
            float4 xc = *(const float4*)(xr + 8);
            float xv[12] = {xa.x, xa.y, xa.z, xa.w,
                            xbv.x, xbv.y, xbv.z, xbv.w,
                            xc.x, xc.y, xc.z, xc.w};
            const float* wr = &ws_s[cur][p * 160 + oc0];
            float4 w0 = *(const float4*)(wr);
            float4 w1v = *(const float4*)(wr + 32);
            float4 w2v = *(const float4*)(wr + 64);
            float4 w3v = *(const float4*)(wr + 96);
            float4 w4v = *(const float4*)(wr + 128);
            float wj[5][4] = {{w0.x, w0.y, w0.z, w0.w},
                              {w1v.x, w1v.y, w1v.z, w1v.w},
                              {w2v.x, w2v.y, w2v.z, w2v.w},
                              {w3v.x, w3v.y, w3v.z, w3v.w},
                              {w4v.x, w4v.y, w4v.z, w4v.w}};
#pragma unroll
            for (int j = 0; j < 5; ++j)
#pragma unroll
                for (int jt = 0; jt < 8; ++jt) {
                    float xx = xv[jt + j];
#pragma unroll
                    for (int jo = 0; jo < 4; ++jo)
                        acc[jo][jt] = fmaf(wj[j][jo], xx, acc[jo][jt]);
                }
        }
        __syncthreads();                      // stage(ic+1) visible; buf[cur] free
    }

    float bias[4];
#pragma unroll
    for (int jo = 0; jo < 4; ++jo) bias[jo] = b1[oc0 + jo];

    bool tvalid = (t0 + lt0) <= (T1 - 8);
    float psum[4], psq[4];
#pragma unroll
    for (int jo = 0; jo < 4; ++jo) {
        float s = 0.f, q = 0.f;
        if (tvalid) {
            float tmp[8];
#pragma unroll
            for (int jt = 0; jt < 8; ++jt) {
                float v = acc[jo][jt] + bias[jo];
                tmp[jt] = v; s += v; q = fmaf(v, v, q);
            }
            float* yrow = y1 + (size_t)(b * 32 + oc0 + jo) * T1 + t0 + lt0;
            float4 o0; o0.x = tmp[0]; o0.y = tmp[1]; o0.z = tmp[2]; o0.w = tmp[3];
            float4 o1; o1.x = tmp[4]; o1.y = tmp[5]; o1.z = tmp[6]; o1.w = tmp[7];
            *(float4*)yrow       = o0;
            *(float4*)(yrow + 4) = o1;
        }
        psum[jo] = s; psq[jo] = q;
    }
#pragma unroll
    for (int off = 32; off >= 8; off >>= 1) {
#pragma unroll
        for (int jo = 0; jo < 4; ++jo) {
            psum[jo] += __shfl_down(psum[jo], off, 64);
            psq[jo]  += __shfl_down(psq[jo],  off, 64);
        }
    }
    int lane = tid & 63, wvi = tid >> 6;      // 4 waves
    if (lane < 8) {
#pragma unroll
        for (int jo = 0; jo < 4; ++jo) {
            sred[((wvi * 8 + lane) * 4 + jo) * 2 + 0] = psum[jo];
            sred[((wvi * 8 + lane) * 4 + jo) * 2 + 1] = psq[jo];
        }
    }
    __syncthreads();
    if (tid < 64) {
        int oc = tid >> 1, which = tid & 1;
        int og = oc >> 2, jo = oc & 3;        // oc = 4*ocg + jo
        float v = 0.f;
#pragma unroll
        for (int w = 0; w < 4; ++w)
            v += sred[((w * 8 + og) * 4 + jo) * 2 + which];
        atomicAdd(&stats[which * 32 + oc], v);
    }
}

// ---------------- conv2 (BN1+ReLU folded at stage time) + BN2 stats ------------
// R9 form, frozen: in-block ic-split, 384 threads = two 192-thread halves, each
// running the bit-identical R7 dbuf loop over 16 ics; half 1 parks partials in
// LDS; half 0 combines + bias + y2 write + BN2 stats.
__global__ __launch_bounds__(384, 2) void conv2_kernel(const float* __restrict__ b2,
                                                       const float* __restrict__ g1,
                                                       const float* __restrict__ be1,
                                                       float* __restrict__ ws) {
    const float* w2p = ws + OFS_W2P;
    const float* y1 = ws + OFS_Y1;
    float* y2 = ws + OFS_Y2;
    float* stats = ws + OFS_STATS;
    int b = blockIdx.x;
    int tid = threadIdx.x;
    int hf = (tid >= 192) ? 1 : 0;
    int ltid = tid - hf * 192;
    int icbase = hf * 16;
    int ocg = ltid & 7, tg = ltid >> 3;
    int oc0 = ocg * 4, lt0 = tg * 4;

    __shared__ __align__(16) float a1s[2][2][500];   // [hf][buf][5*100] polyphase
    __shared__ __align__(16) float w2s[2][2][800];   // [hf][buf][p*j*oc]
    __shared__ __align__(16) float comb[16 * 192];   // half-1 partials
    __shared__ float sred[192];
    __shared__ float bns[64];                        // BN1 scale/shift

    if (tid < 32) {
        float mean = stats[tid] * (1.f / 253952.f);
        float var  = stats[32 + tid] * (1.f / 253952.f) - mean * mean;
        float s = g1[tid] * rsqrtf(var + 1e-5f);
        bns[tid]      = s;
        bns[32 + tid] = be1[tid] - mean * s;
    }

    float acc[4][4];
#pragma unroll
    for (int a = 0; a < 4; ++a)
#pragma unroll
        for (int c = 0; c < 4; ++c) acc[a][c] = 0.f;

    float4 py, pw0, pw1;
    auto fetch = [&](int k) {
        int ic = icbase + k;
        const float* yrow = y1 + (size_t)(b * 32 + ic) * T1;
        if (ltid < 124) py = *(const float4*)(yrow + 4 * ltid);
        pw0 = *(const float4*)(w2p + ic * 800 + 4 * ltid);          // ltid < 192 < 200
        if (ltid < 8) pw1 = *(const float4*)(w2p + ic * 800 + 4 * (ltid + 192));
    };

    auto stage = [&](int k, int cur) {
        int ic = icbase + k;
        if (ltid < 124) {
            float s1 = bns[ic], sh1 = bns[32 + ic];
            float vals[4];
            vals[0] = fmaxf(fmaf(py.x, s1, sh1), 0.f);
            vals[1] = fmaxf(fmaf(py.y, s1, sh1), 0.f);
            vals[2] = fmaxf(fmaf(py.z, s1, sh1), 0.f);
            vals[3] = fmaxf(fmaf(py.w, s1, sh1), 0.f);
            int g = 4 * ltid;
            int col = g / 5, p = g - 5 * col;
#pragma unroll
            for (int m = 0; m < 4; ++m) {
                int pm = p + m;
                int rr = (pm >= 5) ? pm - 5 : pm;
                int cc = col + ((pm >= 5) ? 1 : 0);
                a1s[hf][cur][rr * 100 + cc] = vals[m];
            }
        }
        *(float4*)&w2s[hf][cur][4 * ltid] = pw0;
        if (ltid < 8) *(float4*)&w2s[hf][cur][4 * (ltid + 192)] = pw1;
    };

    fetch(0);
    __syncthreads();                          // bns visible
    stage(0, 0);
    fetch(1);
    __syncthreads();                          // buf0 visible

    for (int k = 0; k < 16; ++k) {
        int cur = k & 1;
        if (k + 1 < 16) stage(k + 1, cur ^ 1);    // stage next while computing cur
        if (k + 2 < 16) fetch(k + 2);             // loads fly during compute

#pragma unroll 2
        for (int p = 0; p < 5; ++p) {
            const float* xr = &a1s[hf][cur][p * 100 + 4 * tg];
            float4 xa = *(const float4*)(xr);
            float4 xbv = *(const float4*)(xr + 4);
            float xv[8] = {xa.x, xa.y, xa.z, xa.w, xbv.x, xbv.y, xbv.z, xbv.w};
            const float* wr = &w2s[hf][cur][p * 160 + oc0];
            float4 w0 = *(const float4*)(wr);
            float4 w1v = *(const float4*)(wr + 32);
            float4 w2v = *(const float4*)(wr + 64);
            float4 w3v = *(const float4*)(wr + 96);
            float4 w4v = *(const float4*)(wr + 128);
            float wj[5][4] = {{w0.x, w0.y, w0.z, w0.w},
                              {w1v.x, w1v.y, w1v.z, w1v.w},
                              {w2v.x, w2v.y, w2v.z, w2v.w},
                              {w3v.x, w3v.y, w3v.z, w3v.w},
                              {w4v.x, w4v.y, w4v.z, w4v.w}};
#pragma unroll
            for (int j = 0; j < 5; ++j)
#pragma unroll
                for (int jt = 0; jt < 4; ++jt) {
                    float xx = xv[jt + j];
#pragma unroll
                    for (int jo = 0; jo < 4; ++jo)
                        acc[jo][jt] = fmaf(wj[j][jo], xx, acc[jo][jt]);
                }
        }
        __syncthreads();                      // stage(k+1) visible; buf[cur] free
    }

    // half 1 parks partials (stride-1 across lanes: conflict-free)
    if (hf == 1) {
#pragma unroll
        for (int jo = 0; jo < 4; ++jo)
#pragma unroll
            for (int jt = 0; jt < 4; ++jt)
                comb[(jo * 4 + jt) * 192 + ltid] = acc[jo][jt];
    }
    __syncthreads();

    if (hf == 0) {
        float bias[4];
#pragma unroll
        for (int jo = 0; jo < 4; ++jo) bias[jo] = b2[oc0 + jo];

        float psum[4], psq[4];
#pragma unroll
        for (int jo = 0; jo < 4; ++jo) {
            float s = 0.f, q = 0.f;
#pragma unroll
            for (int jt = 0; jt < 4; ++jt) {
                int t2 = lt0 + jt;
                if (t2 < T2) {
                    float v = acc[jo][jt] + comb[(jo * 4 + jt) * 192 + ltid] + bias[jo];
                    y2[(size_t)(b * 32 + oc0 + jo) * T2 + t2] = v;
                    s += v; q = fmaf(v, v, q);
                }
            }
            psum[jo] = s; psq[jo] = q;
        }
#pragma unroll
        for (int off = 32; off >= 8; off >>= 1) {
#pragma unroll
            for (int jo = 0; jo < 4; ++jo) {
                psum[jo] += __shfl_down(psum[jo], off, 64);
                psq[jo]  += __shfl_down(psq[jo],  off, 64);
            }
        }
        int lane = ltid & 63, wvi = ltid >> 6;   // 3 waves
        if (lane < 8) {
#pragma unroll
            for (int jo = 0; jo < 4; ++jo) {
                sred[((wvi * 8 + lane) * 4 + jo) * 2 + 0] = psum[jo];
                sred[((wvi * 8 + lane) * 4 + jo) * 2 + 1] = psq[jo];
            }
        }
    }
    __syncthreads();
    if (tid < 64) {
        int oc = tid >> 1, which = tid & 1;
        int og = oc >> 2, jo = oc & 3;
        float v = 0.f;
#pragma unroll
        for (int w = 0; w < 3; ++w)
            v += sred[((w * 8 + og) * 4 + jo) * 2 + which];
        atomicAdd(&stats[64 + which * 32 + oc], v);
    }
}

// ---------------- projection + LayerNorm, writes xs[t][b][l] ----------------
// R9 form (standalone).
__global__ __launch_bounds__(256, 2) void proj_kernel(const float* __restrict__ g2,
                                                      const float* __restrict__ be2,
                                                      const float* __restrict__ pw,
                                                      const float* __restrict__ pb,
                                                      const float* __restrict__ lng,
                                                      const float* __restrict__ lnb,
                                                      float* __restrict__ ws) {
    int b = blockIdx.x;
    int tid = threadIdx.x;
    __shared__ float a2s[3040];       // [f][t]
    __shared__ float pws[1056];       // [l][33]
    __shared__ float bns2[64];
    const float* stats = ws + OFS_STATS;
    const float* y2 = ws + OFS_Y2 + (size_t)b * (32 * T2);
    float* xsg = ws + OFS_XS;

    if (tid < 32) {
        float mean = stats[64 + tid] * (1.f / 48640.f);
        float var  = stats[96 + tid] * (1.f / 48640.f) - mean * mean;
        float s = g2[tid] * rsqrtf(var + 1e-5f);
        bns2[tid]      = s;
        bns2[32 + tid] = be2[tid] - mean * s;
    }
    __syncthreads();

    for (int i = tid; i < 3040; i += 256) {
        int f = i / 95;
        a2s[i] = fmaxf(fmaf(y2[i], bns2[f], bns2[32 + f]), 0.f);
    }
    for (int i = tid; i < 1024; i += 256)
        pws[(i >> 5) * 33 + (i & 31)] = pw[i];

    int l = tid & 31, ts = tid >> 5;
    float pbv = pb[l], lg = lng[l], lb = lnb[l];
    __syncthreads();

    for (int it = 0; it < 12; ++it) {
        int t = ts + 8 * it;
        if (t < T2) {
            float v = pbv;
#pragma unroll
            for (int f = 0; f < 32; ++f)
                v = fmaf(a2s[f * T2 + t], pws[l * 33 + f], v);
            float sum = v;
#pragma unroll
            for (int off = 16; off >= 1; off >>= 1) sum += __shfl_xor(sum, off, 64);
            float mean = sum * (1.f / 32.f);
            float d = v - mean;
            float q = d * d;
#pragma unroll
            for (int off = 16; off >= 1; off >>= 1) q += __shfl_xor(q, off, 64);
            float o = d * rsqrtf(q * (1.f / 32.f) + 1e-5f) * lg + lb;
            xsg[(size_t)t * (NB * 32) + b * 32 + l] = o;
        }
    }
}

// ---------------- PLRNN scan + pooled mean + output projection ----------------
// R12: all __syncthreads() REMOVED — block = 64 threads = exactly one wave, so
// every barrier was a semantic no-op, but each cost the compiler-emitted
// `s_waitcnt vmcnt(0) lgkmcnt(0)` drain before s_barrier, which landed between
// the xv global prefetch and its use: ~95 exposed L2/L3 latencies per block.
// Single-wave correctness: lockstep + in-order LDS pipe; hds/hs write->read are
// same-array accesses the compiler keeps ordered via lgkmcnt (this barrier-free
// body already ran and passed inside R10's fused kernel).
__global__ __launch_bounds__(64)
__attribute__((amdgpu_waves_per_eu(1, 1)))
void scan_kernel(const float* __restrict__ Am,
                 const float* __restrict__ Wm,
                 const float* __restrict__ hbp,
                 const float* __restrict__ ow,
                 const float* __restrict__ ob,
                 const float* __restrict__ ws,
                 float* __restrict__ out) {
    int b = blockIdx.x;
    int lane = threadIdx.x;
    int l = lane & 31, half = lane >> 5;
    __shared__ __align__(16) float hs[32];
    __shared__ __align__(16) float hds[64];
    __shared__ float ows[1056];

    float Wc[32], WT[32], Ah[16];
#pragma unroll
    for (int j = 0; j < 32; ++j) Wc[j] = Wm[j * HIDD + lane];          // W[j][lane]
#pragma unroll
    for (int m = 0; m < 32; ++m) WT[m] = Wm[l * HIDD + half * 32 + m]; // W[l][m-half]
#pragma unroll
    for (int j = 0; j < 16; ++j) Ah[j] = Am[l * 32 + half * 16 + j];   // A[l][j-half]
    float hbv = hbp[lane];
    for (int i = lane; i < 1024; i += 64)
        ows[(i >> 5) * 33 + (i & 31)] = ow[i];

    const float* xsg = ws + OFS_XS + b * 32;
    if (lane < 32) hs[l] = 0.f;
    float xv = xsg[l];
    float pool = 0.f;

    for (int t = 0; t < T2; ++t) {
        float4 hv[8];
#pragma unroll
        for (int q = 0; q < 8; ++q) hv[q] = *(const float4*)&hs[4 * q];
        float a0 = hbv, a1 = 0.f, a2 = 0.f, a3 = 0.f;
#pragma unroll
        for (int q = 0; q < 8; ++q) {
            a0 = fmaf(Wc[4 * q + 0], hv[q].x, a0);
            a1 = fmaf(Wc[4 * q + 1], hv[q].y, a1);
            a2 = fmaf(Wc[4 * q + 2], hv[q].z, a2);
            a3 = fmaf(Wc[4 * q + 3], hv[q].w, a3);
        }
        float hid = fmaxf((a0 + a1) + (a2 + a3), 0.f);
        float4 hl[4];
#pragma unroll
        for (int q = 0; q < 4; ++q) hl[q] = *(const float4*)&hs[half * 16 + 4 * q];
        float l0 = 0.f, l1 = 0.f;
#pragma unroll
        for (int q = 0; q < 4; ++q) {
            l0 = fmaf(Ah[4 * q + 0], hl[q].x, l0);
            l1 = fmaf(Ah[4 * q + 1], hl[q].y, l1);
            l0 = fmaf(Ah[4 * q + 2], hl[q].z, l0);
            l1 = fmaf(Ah[4 * q + 3], hl[q].w, l1);
        }
        float lin = l0 + l1;
        hds[lane] = hid;
        float n0 = 0.f, n1 = 0.f, n2 = 0.f, n3 = 0.f;
#pragma unroll
        for (int q = 0; q < 8; ++q) {
            float4 d4 = *(const float4*)&hds[half * 32 + 4 * q];
            n0 = fmaf(WT[4 * q + 0], d4.x, n0);
            n1 = fmaf(WT[4 * q + 1], d4.y, n1);
            n2 = fmaf(WT[4 * q + 2], d4.z, n2);
            n3 = fmaf(WT[4 * q + 3], d4.w, n3);
        }
        float part = (n0 + n1) + (n2 + n3) + lin;
        part += __shfl_xor(part, 32, 64);
        float hnew = part + xv;
        pool += hnew;
        if (t + 1 < T2) xv = xsg[(size_t)(t + 1) * (NB * 32) + l];
        if (lane < 32) hs[l] = hnew;
    }

    if (lane < 32) hs[l] = pool * (1.f / 95.f);
    if (lane < 32) {
        float4 p0 = *(const float4*)&hs[0];
        float4 p1 = *(const float4*)&hs[4];
        float4 p2 = *(const float4*)&hs[8];
        float4 p3 = *(const float4*)&hs[12];
        float4 p4 = *(const float4*)&hs[16];
        float4 p5 = *(const float4*)&hs[20];
        float4 p6 = *(const float4*)&hs[24];
        float4 p7 = *(const float4*)&hs[28];
        float o = ob[l];
        const float* owr = &ows[l * 33];
        o = fmaf(owr[0],  p0.x, o); o = fmaf(owr[1],  p0.y, o);
        o = fmaf(owr[2],  p0.z, o); o = fmaf(owr[3],  p0.w, o);
        o = fmaf(owr[4],  p1.x, o); o = fmaf(owr[5],  p1.y, o);
        o = fmaf(owr[6],  p1.z, o); o = fmaf(owr[7],  p1.w, o);
        o = fmaf(owr[8],  p2.x, o); o = fmaf(owr[9],  p2.y, o);
        o = fmaf(owr[10], p2.z, o); o = fmaf(owr[11], p2.w, o);
        o = fmaf(owr[12], p3.x, o); o = fmaf(owr[13], p3.y, o);
        o = fmaf(owr[14], p3.z, o); o = fmaf(owr[15], p3.w, o);
        o = fmaf(owr[16], p4.x, o); o = fmaf(owr[17], p4.y, o);
        o = fmaf(owr[18], p4.z, o); o = fmaf(owr[19], p4.w, o);
        o = fmaf(owr[20], p5.x, o); o = fmaf(owr[21], p5.y, o);
        o = fmaf(owr[22], p5.z, o); o = fmaf(owr[23], p5.w, o);
        o = fmaf(owr[24], p6.x, o); o = fmaf(owr[25], p6.y, o);
        o = fmaf(owr[26], p6.z, o); o = fmaf(owr[27], p6.w, o);
        o = fmaf(owr[28], p7.x, o); o = fmaf(owr[29], p7.y, o);
        o = fmaf(owr[30], p7.z, o); o = fmaf(owr[31], p7.w, o);
        out[b * 32 + l] = o;
    }
}

extern "C" void kernel_launch(void* const* d_in, const int* in_sizes, int n_in,
                              void* d_out, int out_size, void* d_ws, size_t ws_size,
                              hipStream_t stream) {
    (void)in_sizes; (void)n_in; (void)out_size; (void)ws_size;
    const float* x   = (const float*)d_in[0];
    const float* w1  = (const float*)d_in[1];
    const float* b1  = (const float*)d_in[2];
    const float* g1  = (const float*)d_in[3];
    const float* be1 = (const float*)d_in[4];
    const float* w2  = (const float*)d_in[5];
    const float* b2  = (const float*)d_in[6];
    const float* g2  = (const float*)d_in[7];
    const float* be2 = (const float*)d_in[8];
    const float* pw  = (const float*)d_in[9];
    const float* pb  = (const float*)d_in[10];
    const float* lng = (const float*)d_in[11];
    const float* lnb = (const float*)d_in[12];
    const float* Am  = (const float*)d_in[13];
    const float* Wm  = (const float*)d_in[14];
    const float* hb  = (const float*)d_in[15];
    const float* ow  = (const float*)d_in[16];
    const float* ob  = (const float*)d_in[17];
    float* ws  = (float*)d_ws;
    float* out = (float*)d_out;

    prep_kernel<<<176, 256, 0, stream>>>(w1, w2, ws);
    conv1_kernel<<<1024, 256, 0, stream>>>(x, b1, ws);
    conv2_kernel<<<512, 384, 0, stream>>>(b2, g1, be1, ws);
    proj_kernel<<<512, 256, 0, stream>>>(g2, be2, pw, pb, lng, lnb, ws);
    scan_kernel<<<512, 64, 0, stream>>>(Am, Wm, hb, ow, ob, ws, out);
}